// Round 6
// baseline (773.320 us; speedup 1.0000x reference)
//
#include <hip/hip_runtime.h>

// VGG16-A spiking NN, multi-compartment LIF (K=2), T=3, B=4, fp32.
// Round 12: conv_mid3 stencil via cooperative LDS halo-tile staging.
//  - r11 counters (VALU 35%, HBM 2.8%, occ 20%, 60us dispatches): latency-
//    bound on 27 gathered L2 loads + 27 cndmasks per ic-iter per lane.
//  - New conv_mid3: per round, 512 threads stage NW=8 channels' 3-timestep
//    halo tiles into LDS (coalesced, zero-filled halo, double-buffered,
//    ONE barrier/round); waves read taps via ds_read (short latency) and
//    FMA. Masks execute once per element at stage time, not per tap.
//  - Work partition / grid / epilogue / all other kernels unchanged (r11).

#define BATCH 4

__device__ __forceinline__ float lif_update(float mem_in, float syn, float thr,
                                            float leak, float* mem_out) {
    float m = leak * mem_in + syn;
    float val = 0.f;
    if ((m / thr - 1.f > 0.f) && (1.f - m / (2.f * thr) >= 0.f)) val += 1.f;
    if ((m / (2.f * thr) - 1.f > 0.f) && (1.f - m / (4.f * thr) >= 0.f)) val += 2.f;
    *mem_out = m - thr * val;
    return val;
}

// Layer 0: conv(x,w0) computed once (timestep-invariant), 3 LIF steps in
// registers, 3 spike outputs.
__global__ void conv_lif0_kernel(const float* __restrict__ in,
                                 const float* __restrict__ w,
                                 float* __restrict__ out0,
                                 float* __restrict__ out1,
                                 float* __restrict__ out2,
                                 const float* __restrict__ thr_v,
                                 const float* __restrict__ leak_v,
                                 int IC, int OC, int H, int W, int n) {
    int idx = blockIdx.x * blockDim.x + threadIdx.x;
    if (idx >= n) return;
    int x  = idx % W;
    int y  = (idx / W) % H;
    int oc = (idx / (W * H)) % OC;
    int b  = idx / (W * H * OC);

    const float* wp = w + (size_t)oc * IC * 9;
    const float* ip = in + (size_t)b * IC * H * W;

    float syn = 0.f;
    for (int ic = 0; ic < IC; ++ic) {
        const float* ipc = ip + (size_t)ic * H * W;
        const float* wpc = wp + ic * 9;
#pragma unroll
        for (int ky = 0; ky < 3; ++ky) {
            int yy = y + ky - 1;
            if (yy < 0 || yy >= H) continue;
#pragma unroll
            for (int kx = 0; kx < 3; ++kx) {
                int xx = x + kx - 1;
                if (xx < 0 || xx >= W) continue;
                syn = fmaf(ipc[yy * W + xx], wpc[ky * 3 + kx], syn);
            }
        }
    }
    float thr = thr_v[0], leak = leak_v[0];
    float m = 0.f;
    float v0 = lif_update(m, syn, thr, leak, &m);
    float v1 = lif_update(m, syn, thr, leak, &m);
    float v2 = lif_update(m, syn, thr, leak, &m);
    out0[idx] = v0;
    out1[idx] = v1;
    out2[idx] = v2;
}

// Cooperative halo-tile staging: NW channels x 3 timesteps x TILE px into
// dst (linear [icg][t][p]). Halo zero-filled here (no masks in compute).
template <int NW, int W_>
__device__ __forceinline__ void stage_tiles(float* __restrict__ dst, int tid,
                                            int rnd, int icpw, int y0,
                                            const float* __restrict__ i0,
                                            const float* __restrict__ i1,
                                            const float* __restrict__ i2) {
    constexpr int TWD = W_ + 2;
    constexpr int TH = 64 / W_ + 2;
    constexpr int TILE = TH * TWD;
    constexpr int HW = W_ * W_;
    constexpr int TOT = NW * 3 * TILE;
    for (int s = tid; s < TOT; s += NW * 64) {
        int icg = s / (3 * TILE);
        int rem = s - icg * 3 * TILE;
        int t = rem / TILE;
        int p = rem - t * TILE;
        int r = p / TWD;
        int c = p - r * TWD;
        int ic = icg * icpw + rnd;
        int gy = y0 + r - 1;
        int gx = c - 1;
        const float* pt = (t == 0) ? i0 : ((t == 1) ? i1 : i2);
        float val = 0.f;
        if (gy >= 0 && gy < W_ && gx >= 0 && gx < W_)
            val = pt[(size_t)ic * HW + gy * W_ + gx];
        dst[s] = val;
    }
}

// Layers 1-6, 3 timesteps fused, LDS-staged stencil. Block = NW waves.
// blockIdx -> (b, pixel-chunk, oc-group). Wave wv handles its IC/NW
// channels (one per round; tiles staged cooperatively, double-buffered);
// LDS reduce across waves; in-register membrane LIF; optional fused pool.
template <int OCT, int NW, int POOL, int W_>
__global__ __launch_bounds__(NW * 64)
void conv_mid3_kernel(const float* __restrict__ in0,
                      const float* __restrict__ in1,
                      const float* __restrict__ in2,
                      const float* __restrict__ w,
                      float* __restrict__ out0,
                      float* __restrict__ out1,
                      float* __restrict__ out2,
                      const float* __restrict__ thr_v,
                      const float* __restrict__ leak_v,
                      int layer, int IC, int OC) {
    constexpr int HW = W_ * W_;
    constexpr int RPW = 64 / W_;
    constexpr int TH = RPW + 2;
    constexpr int TWD = W_ + 2;
    constexpr int TILE = TH * TWD;
    constexpr int CHUNKS = HW / 64;

    int tid = threadIdx.x;
    int lane = tid & 63;
    int wv = tid >> 6;  // 0..NW-1
    int ocg = OC / OCT;
    int bid = blockIdx.x;
    int g  = bid % ocg;
    int ch = (bid / ocg) % CHUNKS;
    int b  = bid / (ocg * CHUNKS);
    int y0 = ch * RPW;
    int oc0 = g * OCT;

    size_t boff = (size_t)b * IC * HW;
    const float* i0 = in0 + boff;
    const float* i1 = in1 + boff;
    const float* i2 = in2 + boff;
    float* const outs[3] = {out0, out1, out2};
    const float* wbase = w + (size_t)oc0 * IC * 9;

    int icpw = IC / NW;

    __shared__ float stage[2][NW * 3 * TILE];

    float acc[3][OCT];
#pragma unroll
    for (int t = 0; t < 3; ++t)
#pragma unroll
        for (int q = 0; q < OCT; ++q) acc[t][q] = 0.f;

    int r0 = lane / W_;
    int c0 = lane % W_;

    stage_tiles<NW, W_>(stage[0], tid, 0, icpw, y0, i0, i1, i2);
    __syncthreads();

    for (int rnd = 0; rnd < icpw; ++rnd) {
        int buf = rnd & 1;
        if (rnd + 1 < icpw)
            stage_tiles<NW, W_>(stage[buf ^ 1], tid, rnd + 1, icpw, y0, i0, i1, i2);

        // this wave's channel weights (lane-uniform -> scalarized)
        int ic = wv * icpw + rnd;
        const float* wp = wbase + (size_t)ic * 9;
        float wvv[OCT][9];
#pragma unroll
        for (int q = 0; q < OCT; ++q) {
            const float* wq = wp + (size_t)q * IC * 9;
#pragma unroll
            for (int k = 0; k < 9; ++k) wvv[q][k] = wq[k];
        }

        const float* sb = stage[buf] + wv * (3 * TILE);
#pragma unroll
        for (int t = 0; t < 3; ++t) {
            const float* tp = sb + t * TILE + r0 * TWD + c0;
            float tv[9];
#pragma unroll
            for (int ky = 0; ky < 3; ++ky)
#pragma unroll
                for (int kx = 0; kx < 3; ++kx)
                    tv[ky * 3 + kx] = tp[ky * TWD + kx];
#pragma unroll
            for (int q = 0; q < OCT; ++q)
#pragma unroll
                for (int k = 0; k < 9; ++k)
                    acc[t][q] = fmaf(tv[k], wvv[q][k], acc[t][q]);
        }
        __syncthreads();  // staged buf ready for next round; this buf free
    }

    __shared__ float red[NW][OCT][64];
    __shared__ float vals[OCT][64];
    float thr = thr_v[layer], leak = leak_v[layer];
    float mem_reg = 0.f;  // membrane carried in-register across timesteps
    int eq = tid >> 6, ep = tid & 63;
    constexpr int Wo = W_ / 2, Ho = W_ / 2;

#pragma unroll
    for (int t = 0; t < 3; ++t) {
        __syncthreads();  // protect red/vals from previous timestep's readers
#pragma unroll
        for (int q = 0; q < OCT; ++q) red[wv][q][lane] = acc[t][q];
        __syncthreads();
        if (tid < OCT * 64) {
            float sum = 0.f;
#pragma unroll
            for (int q = 0; q < NW; ++q) sum += red[q][eq][ep];
            float val = lif_update(mem_reg, sum, thr, leak, &mem_reg);
            if (POOL) {
                vals[eq][ep] = val;
            } else {
                size_t idx = (size_t)(b * OC + oc0 + eq) * HW + ch * 64 + ep;
                outs[t][idx] = val;
            }
        }
        if (POOL) {
            __syncthreads();
            if (tid < OCT * 16) {
                int q = tid >> 4, s = tid & 15;
                int pr = s / Wo, pc = s % Wo;
                float pv = 0.25f * (vals[q][(2 * pr) * W_ + 2 * pc] +
                                    vals[q][(2 * pr) * W_ + 2 * pc + 1] +
                                    vals[q][(2 * pr + 1) * W_ + 2 * pc] +
                                    vals[q][(2 * pr + 1) * W_ + 2 * pc + 1]);
                size_t pidx = ((size_t)(b * OC + oc0 + q) * Ho +
                               (ch * (RPW >> 1) + pr)) * Wo + pc;
                outs[t][pidx] = pv;
            }
        }
    }
}

// Layers 7-12 (4x4 / 2x2 planes), 3 timesteps fused (sequential passes,
// membrane in-register). Block = NW waves, one oc per block.
template <int S, int NW, int POOL>
__global__ __launch_bounds__(NW * 64)
void conv_small4_3_kernel(const float* __restrict__ in0,
                          const float* __restrict__ in1,
                          const float* __restrict__ in2,
                          const float* __restrict__ w,
                          float* __restrict__ out0,
                          float* __restrict__ out1,
                          float* __restrict__ out2,
                          const float* __restrict__ thr_v,
                          const float* __restrict__ leak_v,
                          int layer, int IC, int OC) {
    constexpr int SS = S * S;
    constexpr int M = 4 * SS;              // 64 (S=4) or 16 (S=2)
    constexpr int LOG2M = (S == 4) ? 6 : 4;
    int tid = threadIdx.x;
    int lane = tid & 63;
    int wv = tid >> 6;  // 0..NW-1
    int oc = blockIdx.x;

    const float* const ins[3] = {in0, in1, in2};
    float* const outs[3] = {out0, out1, out2};
    const float* wrow = w + (size_t)oc * IC * 9;

    __shared__ float red[NW][M];
    __shared__ float pvs[M];
    float thr = thr_v[layer], leak = leak_v[layer];
    float mem_reg = 0.f;  // for tid < M

#pragma unroll
    for (int t = 0; t < 3; ++t) {
        const float* inb = ins[t];
        float acc[M];
#pragma unroll
        for (int i = 0; i < M; ++i) acc[i] = 0.f;

        for (int ic = lane + (wv << 6); ic < IC; ic += NW * 64) {
            const float* wp = wrow + (size_t)ic * 9;
            float wvv[9];
#pragma unroll
            for (int k = 0; k < 9; ++k) wvv[k] = wp[k];
#pragma unroll
            for (int b = 0; b < 4; ++b) {
                const float4* ip = (const float4*)(inb + (size_t)(b * IC + ic) * SS);
                float pv[SS];
#pragma unroll
                for (int q = 0; q < SS / 4; ++q) {
                    float4 t4 = ip[q];
                    pv[4 * q + 0] = t4.x;
                    pv[4 * q + 1] = t4.y;
                    pv[4 * q + 2] = t4.z;
                    pv[4 * q + 3] = t4.w;
                }
#pragma unroll
                for (int y = 0; y < S; ++y)
#pragma unroll
                    for (int x = 0; x < S; ++x) {
                        float a = acc[b * SS + y * S + x];
#pragma unroll
                        for (int ky = 0; ky < 3; ++ky) {
                            int yy = y + ky - 1;
                            if (yy < 0 || yy >= S) continue;
#pragma unroll
                            for (int kx = 0; kx < 3; ++kx) {
                                int xx = x + kx - 1;
                                if (xx < 0 || xx >= S) continue;
                                a = fmaf(pv[yy * S + xx], wvv[ky * 3 + kx], a);
                            }
                        }
                        acc[b * SS + y * S + x] = a;
                    }
            }
        }

        // per-wave transpose-reduce: M accs across 64 lanes -> 1 per lane
#pragma unroll
        for (int step = 0; step < LOG2M; ++step) {
            const int offx = 1 << step;
            const int half = M >> (step + 1);
            const bool hi = (lane & offx) != 0;
#pragma unroll
            for (int i = 0; i < half; ++i) {
                float sent = hi ? acc[i] : acc[i + half];
                float got = __shfl_xor(sent, offx);
                acc[i] = (hi ? acc[i + half] : acc[i]) + got;
            }
        }
        float sum = acc[0];
#pragma unroll
        for (int offx = M; offx < 64; offx <<= 1) sum += __shfl_xor(sum, offx);

        __syncthreads();  // protect red/pvs from previous timestep's readers
        int o = (int)(__brev((unsigned)(lane & (M - 1))) >> (32 - LOG2M));
        if (lane < M) red[wv][o] = sum;
        __syncthreads();

        if (tid < M) {
            float tot = 0.f;
#pragma unroll
            for (int q = 0; q < NW; ++q) tot += red[q][tid];
            int b = tid / SS, p = tid % SS;
            float val = lif_update(mem_reg, tot, thr, leak, &mem_reg);
            if (POOL) {
                pvs[tid] = val;
            } else {
                size_t idx = (size_t)(b * OC + oc) * SS + p;
                outs[t][idx] = val;
            }
        }
        if (POOL) {
            __syncthreads();
            constexpr int Sh = S / 2, SSh = Sh * Sh;
            if (tid < 4 * SSh) {
                int b = tid / SSh, q = tid % SSh;
                int pr = q / Sh, pc = q % Sh;
                float pv = 0.25f * (pvs[b * SS + (2 * pr) * S + 2 * pc] +
                                    pvs[b * SS + (2 * pr) * S + 2 * pc + 1] +
                                    pvs[b * SS + (2 * pr + 1) * S + 2 * pc] +
                                    pvs[b * SS + (2 * pr + 1) * S + 2 * pc + 1]);
                outs[t][((size_t)(b * OC + oc) * Sh + pr) * Sh + pc] = pv;
            }
        }
    }
}

// Wave-per-output-neuron FC+LIF, 3 timesteps fused: weight row read ONCE,
// 12 accumulators (3t x 4b), membrane chain at lane 0.
__global__ void fc_lif3_kernel(const float* __restrict__ in0,
                               const float* __restrict__ in1,
                               const float* __restrict__ in2,
                               const float* __restrict__ w,
                               float* __restrict__ out0,
                               float* __restrict__ out1,
                               float* __restrict__ out2,
                               const float* __restrict__ thr_v,
                               const float* __restrict__ leak_v,
                               int layer, int Kd, int N) {
    int wave = (blockIdx.x * blockDim.x + threadIdx.x) >> 6;
    int lane = threadIdx.x & 63;
    if (wave >= N) return;
    int j = wave;
    int K4 = Kd >> 2;
    const float4* wp = (const float4*)(w + (size_t)j * Kd);
    const float4* ip[3] = {(const float4*)in0, (const float4*)in1, (const float4*)in2};
    float* const outs[3] = {out0, out1, out2};

    float a[3][4];
#pragma unroll
    for (int t = 0; t < 3; ++t)
#pragma unroll
        for (int b = 0; b < 4; ++b) a[t][b] = 0.f;

    for (int k = lane; k < K4; k += 64) {
        float4 wv = wp[k];
#pragma unroll
        for (int t = 0; t < 3; ++t)
#pragma unroll
            for (int b = 0; b < 4; ++b) {
                float4 v = ip[t][b * K4 + k];
                a[t][b] = fmaf(wv.x, v.x, fmaf(wv.y, v.y,
                          fmaf(wv.z, v.z, fmaf(wv.w, v.w, a[t][b]))));
            }
    }
#pragma unroll
    for (int t = 0; t < 3; ++t)
#pragma unroll
        for (int b = 0; b < 4; ++b)
#pragma unroll
            for (int off = 32; off > 0; off >>= 1)
                a[t][b] += __shfl_xor(a[t][b], off);

    if (lane == 0) {
        float thr = thr_v[layer], leak = leak_v[layer];
#pragma unroll
        for (int b = 0; b < BATCH; ++b) {
            float m = 0.f;
#pragma unroll
            for (int t = 0; t < 3; ++t) {
                float val = lif_update(m, a[t][b], thr, leak, &m);
                outs[t][(size_t)b * N + j] = val;
            }
        }
    }
}

// One 64-thread block per (b, label). logits = sum_t in_t[b,:] . w[l,:]
__global__ void fc2_acc3_kernel(const float* __restrict__ in0,
                                const float* __restrict__ in1,
                                const float* __restrict__ in2,
                                const float* __restrict__ w,
                                float* __restrict__ logits,
                                int Kd, int L) {
    int o = blockIdx.x;
    int l = o % L;
    int b = o / L;
    int K4 = Kd >> 2;
    const float4* ip[3] = {(const float4*)(in0 + (size_t)b * Kd),
                           (const float4*)(in1 + (size_t)b * Kd),
                           (const float4*)(in2 + (size_t)b * Kd)};
    const float4* wp = (const float4*)(w + (size_t)l * Kd);
    float st[3] = {0.f, 0.f, 0.f};
    for (int k = threadIdx.x; k < K4; k += 64) {
        float4 wv = wp[k];
#pragma unroll
        for (int t = 0; t < 3; ++t) {
            float4 iv = ip[t][k];
            st[t] = fmaf(iv.x, wv.x, fmaf(iv.y, wv.y,
                    fmaf(iv.z, wv.z, fmaf(iv.w, wv.w, st[t]))));
        }
    }
#pragma unroll
    for (int t = 0; t < 3; ++t)
#pragma unroll
        for (int off = 32; off > 0; off >>= 1) st[t] += __shfl_xor(st[t], off);
    if (threadIdx.x == 0) logits[o] = (st[0] + st[1]) + st[2];
}

extern "C" void kernel_launch(void* const* d_in, const int* in_sizes, int n_in,
                              void* d_out, int out_size, void* d_ws, size_t ws_size,
                              hipStream_t stream) {
    const float* x = (const float*)d_in[0];
    const float* convw[13];
    for (int i = 0; i < 13; ++i) convw[i] = (const float*)d_in[1 + i];
    const float* fc0 = (const float*)d_in[14];
    const float* fc1 = (const float*)d_in[15];
    const float* fc2 = (const float*)d_in[16];
    const float* thr = (const float*)d_in[17];
    const float* leak = (const float*)d_in[18];

    static const int IC[13] = {3, 64, 64, 128, 128, 256, 256, 256, 512, 512, 512, 512, 512};
    static const int OC[13] = {64, 64, 128, 128, 256, 256, 256, 512, 512, 512, 512, 512, 512};

    float* ws = (float*)d_ws;
    // two ping-pong sets of 3 timestep buffers, 262144 floats each
    float* A[3];
    float* B[3];
    size_t off = 0;
    for (int i = 0; i < 3; ++i) { A[i] = ws + off; off += 262144; }
    for (int i = 0; i < 3; ++i) { B[i] = ws + off; off += 262144; }

    // L0: conv once + 3 in-register LIF steps -> A
    {
        int n = BATCH * 64 * 32 * 32;
        conv_lif0_kernel<<<(n + 255) / 256, 256, 0, stream>>>(
            x, convw[0], A[0], A[1], A[2], thr, leak, 3, 64, 32, 32, n);
    }

    float** src = A;
    float** dst = B;

    // L1: 64->64 @32x32, pool. blocks = 4 * 16 * 16 = 1024
    conv_mid3_kernel<4, 8, 1, 32><<<BATCH * 16 * (OC[1] / 4), 512, 0, stream>>>(
        src[0], src[1], src[2], convw[1], dst[0], dst[1], dst[2],
        thr, leak, 1, IC[1], OC[1]);
    { float** tmp = src; src = dst; dst = tmp; }

    // L2: 64->128 @16x16. blocks = 4 * 4 * 32 = 512
    conv_mid3_kernel<4, 8, 0, 16><<<BATCH * 4 * (OC[2] / 4), 512, 0, stream>>>(
        src[0], src[1], src[2], convw[2], dst[0], dst[1], dst[2],
        thr, leak, 2, IC[2], OC[2]);
    { float** tmp = src; src = dst; dst = tmp; }

    // L3: 128->128 @16x16, pool. blocks = 512
    conv_mid3_kernel<4, 8, 1, 16><<<BATCH * 4 * (OC[3] / 4), 512, 0, stream>>>(
        src[0], src[1], src[2], convw[3], dst[0], dst[1], dst[2],
        thr, leak, 3, IC[3], OC[3]);
    { float** tmp = src; src = dst; dst = tmp; }

    // L4: 128->256 @8x8. blocks = 4 * 1 * 128 = 512
    conv_mid3_kernel<2, 8, 0, 8><<<BATCH * (OC[4] / 2), 512, 0, stream>>>(
        src[0], src[1], src[2], convw[4], dst[0], dst[1], dst[2],
        thr, leak, 4, IC[4], OC[4]);
    { float** tmp = src; src = dst; dst = tmp; }

    // L5: 256->256 @8x8. blocks = 512
    conv_mid3_kernel<2, 8, 0, 8><<<BATCH * (OC[5] / 2), 512, 0, stream>>>(
        src[0], src[1], src[2], convw[5], dst[0], dst[1], dst[2],
        thr, leak, 5, IC[5], OC[5]);
    { float** tmp = src; src = dst; dst = tmp; }

    // L6: 256->256 @8x8, pool. blocks = 512
    conv_mid3_kernel<2, 8, 1, 8><<<BATCH * (OC[6] / 2), 512, 0, stream>>>(
        src[0], src[1], src[2], convw[6], dst[0], dst[1], dst[2],
        thr, leak, 6, IC[6], OC[6]);
    { float** tmp = src; src = dst; dst = tmp; }

    // L7-L12: conv_small4_3
    for (int i = 7; i <= 12; ++i) {
        if (i == 7)
            conv_small4_3_kernel<4, 4, 0><<<OC[i], 256, 0, stream>>>(
                src[0], src[1], src[2], convw[i], dst[0], dst[1], dst[2],
                thr, leak, i, IC[i], OC[i]);
        else if (i == 8)
            conv_small4_3_kernel<4, 8, 0><<<OC[i], 512, 0, stream>>>(
                src[0], src[1], src[2], convw[i], dst[0], dst[1], dst[2],
                thr, leak, i, IC[i], OC[i]);
        else if (i == 9)
            conv_small4_3_kernel<4, 8, 1><<<OC[i], 512, 0, stream>>>(
                src[0], src[1], src[2], convw[i], dst[0], dst[1], dst[2],
                thr, leak, i, IC[i], OC[i]);
        else
            conv_small4_3_kernel<2, 8, 0><<<OC[i], 512, 0, stream>>>(
                src[0], src[1], src[2], convw[i], dst[0], dst[1], dst[2],
                thr, leak, i, IC[i], OC[i]);
        float** tmp = src; src = dst; dst = tmp;
    }

    // fc0, fc1 (LIF), fc2 (logit accumulate over t)
    fc_lif3_kernel<<<(4096 * 64) / 256, 256, 0, stream>>>(
        src[0], src[1], src[2], fc0, dst[0], dst[1], dst[2],
        thr, leak, 13, 2048, 4096);
    { float** tmp = src; src = dst; dst = tmp; }

    fc_lif3_kernel<<<(4096 * 64) / 256, 256, 0, stream>>>(
        src[0], src[1], src[2], fc1, dst[0], dst[1], dst[2],
        thr, leak, 14, 4096, 4096);
    { float** tmp = src; src = dst; dst = tmp; }

    fc2_acc3_kernel<<<BATCH * 10, 64, 0, stream>>>(
        src[0], src[1], src[2], fc2, (float*)d_out, 4096, 10);
}